// Round 14
// baseline (784.901 us; speedup 1.0000x reference)
//
#include <hip/hip_runtime.h>

// GATv2 stack on MI355X. fp32 throughout (no fp32 MFMA on CDNA4 -> vector ALU).
// R13: degree-descending wave->node permutation (counting sort, 128 bins) for
// LPT scheduling of the latency-bound gat kernels. R12 evidence: VALU ops cut
// 25% -> duration flat, occupancy 58% -> tail imbalance is the bound.

static __device__ __forceinline__ float lrelu(float x, float s) {
    return x > 0.f ? x : s * x;
}

// ---------------- fused degree + proj0 ----------------
__global__ void k_build0(const int* __restrict__ dst, int* __restrict__ cnt,
                         int* __restrict__ rank, int E,
                         const float* __restrict__ x,
                         const float* __restrict__ Wl, const float* __restrict__ bl,
                         const float* __restrict__ Wr, const float* __restrict__ br,
                         float* __restrict__ xl, float* __restrict__ xr, int n) {
    int idx = blockIdx.x * blockDim.x + threadIdx.x;
    if (idx < E) {
        rank[idx] = atomicAdd(&cnt[dst[idx]], 1);
    } else {
        int t = idx - E;
        if (t < n * 64) {
            int i = t >> 6, c = t & 63;
            float x0 = x[2 * i], x1 = x[2 * i + 1];
            xl[t] = x0 * Wl[c] + x1 * Wl[64 + c] + bl[c];
            xr[t] = x0 * Wr[c] + x1 * Wr[64 + c] + br[c];
        }
    }
}

// wave-aggregated segment offset allocation
__global__ void k_segoff(const int* __restrict__ cnt, int* __restrict__ row_start,
                         int* __restrict__ cursor, int n) {
    int i = blockIdx.x * blockDim.x + threadIdx.x;
    int lane = threadIdx.x & 63;
    int v = (i < n) ? cnt[i] + 1 : 0;
    int s = v;
#pragma unroll
    for (int off = 1; off < 64; off <<= 1) {
        int t = __shfl_up(s, off);
        if (lane >= off) s += t;
    }
    int wavetot = __shfl(s, 63);
    int base = 0;
    if (lane == 63) base = atomicAdd(cursor, wavetot);
    base = __shfl(base, 63);
    if (i < n) row_start[i] = base + s - v;
}

// degree histogram (128 bins, clamped)
__global__ void k_hist(const int* __restrict__ cnt, int* __restrict__ hist, int n) {
    int i = blockIdx.x * blockDim.x + threadIdx.x;
    if (i < n) atomicAdd(&hist[min(cnt[i], 127)], 1);
}

// descending-order exclusive bin offsets, single wave (lane l owns rev pos 2l,2l+1)
__global__ void k_binoff(int* __restrict__ hist) {
    int l = threadIdx.x & 63;
    int b0 = 127 - 2 * l, b1 = 126 - 2 * l;
    int h0 = hist[b0], h1 = hist[b1];
    int s = h0 + h1;
    int ex = s;
#pragma unroll
    for (int off = 1; off < 64; off <<= 1) {
        int t = __shfl_up(ex, off);
        if (l >= off) ex += t;
    }
    int base = ex - s;
    hist[b0] = base;
    hist[b1] = base + h0;
}

// scatter nodes into perm in degree-descending bin order
__global__ void k_perm(const int* __restrict__ cnt, int* __restrict__ hist,
                       int* __restrict__ perm, int n) {
    int i = blockIdx.x * blockDim.x + threadIdx.x;
    if (i >= n) return;
    int b = min(cnt[i], 127);
    int pos = atomicAdd(&hist[b], 1);
    perm[pos] = i;
}

__global__ void k_scatter(const int* __restrict__ src, const int* __restrict__ dst,
                          const float* __restrict__ ea, const int* __restrict__ rank,
                          const int* __restrict__ row_start,
                          int* __restrict__ csr_src, float* __restrict__ csr_ea, int E) {
    int e = blockIdx.x * blockDim.x + threadIdx.x;
    if (e >= E) return;
    int pos = row_start[dst[e]] + rank[e];
    csr_src[pos] = src[e];
    *(float2*)(csr_ea + 2 * (size_t)pos) = *(const float2*)(ea + 2 * (size_t)e);
}

__global__ void k_selfloop(const int* __restrict__ row_start, const int* __restrict__ cnt,
                           int* __restrict__ csr_src, float* __restrict__ csr_ea, int n) {
    int i = blockIdx.x * blockDim.x + threadIdx.x;
    if (i >= n) return;
    int p0 = row_start[i], deg = cnt[i];
    float s0 = 0.f, s1 = 0.f;
    for (int p = p0; p < p0 + deg; ++p) {
        s0 += csr_ea[2 * (size_t)p];
        s1 += csr_ea[2 * (size_t)p + 1];
    }
    float c = fmaxf((float)deg, 1.f);
    int pl = p0 + deg;
    csr_src[pl] = i;
    csr_ea[2 * (size_t)pl] = s0 / c;
    csr_ea[2 * (size_t)pl + 1] = s1 / c;
}

// ---------------- layer-0 projection with fused BN (reads hbuf) ----------------
__launch_bounds__(256)
__global__ void k_proj64(const float* __restrict__ h,
                         const float* __restrict__ Wl, const float* __restrict__ bl,
                         const float* __restrict__ Wr, const float* __restrict__ br,
                         const double* __restrict__ stats,
                         const float* __restrict__ bng, const float* __restrict__ bnb,
                         float* __restrict__ xl, float* __restrict__ xr, int n) {
    __shared__ float wsl[4096], wsr[4096], bna[64], bnbb[64];
    int t = threadIdx.x;
    for (int i = t; i < 4096; i += 256) { wsl[i] = Wl[i]; wsr[i] = Wr[i]; }
    if (t < 64) {
        double mu = stats[t] / n;
        double var = stats[64 + t] / n - mu * mu;
        float rs = (float)(1.0 / sqrt(var + 1e-5));
        float a = rs * bng[t];
        bna[t] = a;
        bnbb[t] = bnb[t] - (float)mu * a;
    }
    __syncthreads();
    int rg = t >> 2, cg4 = (t & 3) << 4;
    int r0 = blockIdx.x * 128 + rg * 2;
    float accl[2][16], accr[2][16];
#pragma unroll
    for (int r = 0; r < 2; ++r)
#pragma unroll
        for (int j = 0; j < 16; ++j) { accl[r][j] = 0.f; accr[r][j] = 0.f; }
    for (int k0 = 0; k0 < 64; k0 += 4) {
        float hk[2][4];
#pragma unroll
        for (int r = 0; r < 2; ++r) {
            int gr = r0 + r;
            float4 v = (gr < n) ? *(const float4*)(h + (size_t)gr * 64 + k0)
                                : make_float4(0.f, 0.f, 0.f, 0.f);
            hk[r][0] = v.x; hk[r][1] = v.y; hk[r][2] = v.z; hk[r][3] = v.w;
#pragma unroll
            for (int kk = 0; kk < 4; ++kk)
                hk[r][kk] = lrelu(hk[r][kk] * bna[k0 + kk] + bnbb[k0 + kk], 0.01f);
        }
#pragma unroll
        for (int kk = 0; kk < 4; ++kk) {
            const float* wl = wsl + (k0 + kk) * 64 + cg4;
            const float* wr = wsr + (k0 + kk) * 64 + cg4;
#pragma unroll
            for (int r = 0; r < 2; ++r)
#pragma unroll
                for (int j = 0; j < 16; ++j) {
                    accl[r][j] += hk[r][kk] * wl[j];
                    accr[r][j] += hk[r][kk] * wr[j];
                }
        }
    }
#pragma unroll
    for (int r = 0; r < 2; ++r) {
        int gr = r0 + r;
        if (gr < n) {
            float* ol = xl + (size_t)gr * 64 + cg4;
            float* orr = xr + (size_t)gr * 64 + cg4;
#pragma unroll
            for (int j = 0; j < 16; ++j) {
                ol[j] = accl[r][j] + bl[cg4 + j];
                orr[j] = accr[r][j] + br[cg4 + j];
            }
        }
    }
}

// ---------------- gat node body (shared) ----------------
__device__ __forceinline__ float gat_node(const float* __restrict__ xl,
                                          const float* __restrict__ xr,
                                          const int* __restrict__ row_start,
                                          const int* __restrict__ cnt,
                                          const int* __restrict__ csr_src,
                                          const float* __restrict__ csr_ea,
                                          const float* __restrict__ We,
                                          const float* __restrict__ att,
                                          const float* __restrict__ bias,
                                          int d, int lane, int relu) {
    const int p0 = __builtin_amdgcn_readfirstlane(row_start[d]);
    const int p1 = p0 + __builtin_amdgcn_readfirstlane(cnt[d]) + 1;
    const float we0 = We[lane], we1 = We[64 + lane];
    const float av = att[lane];
    const float xrv = xr[(size_t)d * 64 + lane];

    float den0 = 0.f, acc0 = 0.f;
    float den1 = 0.f, acc1 = 0.f;

    auto step = [&](float xv, float2 ea, bool valid, float& den, float& acc) {
        float tv = lrelu(xv + xrv + ea.x * we0 + ea.y * we1, 0.2f) * av;
        tv += __shfl_xor(tv, 1);
        tv += __shfl_xor(tv, 2);
        if (!valid) tv = -__builtin_inff();
        float w = __expf(tv);
        den += w;
        acc += w * xv;
    };

    for (int p = p0; p < p1; p += 4) {
        int q1 = min(p + 1, p1 - 1), q2 = min(p + 2, p1 - 1), q3 = min(p + 3, p1 - 1);
        int s0 = csr_src[p], s1 = csr_src[q1], s2 = csr_src[q2], s3 = csr_src[q3];
        float2 e0 = *(const float2*)(csr_ea + 2 * (size_t)p);
        float2 e1 = *(const float2*)(csr_ea + 2 * (size_t)q1);
        float2 e2 = *(const float2*)(csr_ea + 2 * (size_t)q2);
        float2 e3 = *(const float2*)(csr_ea + 2 * (size_t)q3);
        float x0 = xl[(size_t)s0 * 64 + lane];
        float x1 = xl[(size_t)s1 * 64 + lane];
        float x2 = xl[(size_t)s2 * 64 + lane];
        float x3 = xl[(size_t)s3 * 64 + lane];
        step(x0, e0, true, den0, acc0);
        step(x1, e1, p + 1 < p1, den1, acc1);
        step(x2, e2, p + 2 < p1, den0, acc0);
        step(x3, e3, p + 3 < p1, den1, acc1);
    }
    float o = (acc0 + acc1) / (den0 + den1) + bias[lane];
    if (relu) o = lrelu(o, 0.01f);
    return o;
}

// plain gat (layer 0 -> hbuf, no relu), degree-sorted wave->node via perm
__launch_bounds__(256)
__global__ void k_gat(const float* __restrict__ xl, const float* __restrict__ xr,
                      const int* __restrict__ row_start, const int* __restrict__ cnt,
                      const int* __restrict__ csr_src, const float* __restrict__ csr_ea,
                      const int* __restrict__ perm,
                      const float* __restrict__ We, const float* __restrict__ att,
                      const float* __restrict__ bias,
                      float* __restrict__ out, int n, int relu) {
    int wv = (blockIdx.x * blockDim.x + threadIdx.x) >> 6;
    int lane = threadIdx.x & 63;
    if (wv >= n) return;
    int d = __builtin_amdgcn_readfirstlane(perm[wv]);
    float o = gat_node(xl, xr, row_start, cnt, csr_src, csr_ea, We, att, bias, d, lane, relu);
    out[(size_t)d * 64 + lane] = o;
}

// gat + fused next-layer dual projection epilogue (per-wave, L1-resident weights)
__launch_bounds__(256)
__global__ void k_gat_proj(const float* __restrict__ xl, const float* __restrict__ xr,
                           const int* __restrict__ row_start, const int* __restrict__ cnt,
                           const int* __restrict__ csr_src, const float* __restrict__ csr_ea,
                           const int* __restrict__ perm,
                           const float* __restrict__ We, const float* __restrict__ att,
                           const float* __restrict__ bias,
                           const float* __restrict__ Wnl, const float* __restrict__ bnl,
                           const float* __restrict__ Wnr, const float* __restrict__ bnr,
                           float* __restrict__ xl_out, float* __restrict__ xr_out, int n) {
    int wv = (blockIdx.x * blockDim.x + threadIdx.x) >> 6;
    int lane = threadIdx.x & 63;
    if (wv >= n) return;
    const int d = __builtin_amdgcn_readfirstlane(perm[wv]);
    float o = gat_node(xl, xr, row_start, cnt, csr_src, csr_ea, We, att, bias, d, lane, 1);
    float a0 = 0.f, a1 = 0.f, b0 = 0.f, b1 = 0.f;
#pragma unroll 8
    for (int k = 0; k < 64; k += 2) {
        float h0 = __shfl(o, k);
        float h1 = __shfl(o, k + 1);
        a0 += h0 * Wnl[k * 64 + lane];
        a1 += h1 * Wnl[(k + 1) * 64 + lane];
        b0 += h0 * Wnr[k * 64 + lane];
        b1 += h1 * Wnr[(k + 1) * 64 + lane];
    }
    xl_out[(size_t)d * 64 + lane] = a0 + a1 + bnl[lane];
    xr_out[(size_t)d * 64 + lane] = b0 + b1 + bnr[lane];
}

// gat + fused FINAL packed projection epilogue
// packed[d] = [f_xl(16) | s_xl(16) | f_xr(16) | s_xr(16)]
__launch_bounds__(256)
__global__ void k_gat_projfin(const float* __restrict__ xl, const float* __restrict__ xr,
                              const int* __restrict__ row_start, const int* __restrict__ cnt,
                              const int* __restrict__ csr_src, const float* __restrict__ csr_ea,
                              const int* __restrict__ perm,
                              const float* __restrict__ We, const float* __restrict__ att,
                              const float* __restrict__ bias,
                              const float* __restrict__ fWl, const float* __restrict__ fbl,
                              const float* __restrict__ fWr, const float* __restrict__ fbr,
                              const float* __restrict__ sWl, const float* __restrict__ sbl,
                              const float* __restrict__ sWr, const float* __restrict__ sbr,
                              float* __restrict__ packed, int n) {
    int wv = (blockIdx.x * blockDim.x + threadIdx.x) >> 6;
    int lane = threadIdx.x & 63;
    if (wv >= n) return;
    const int d = __builtin_amdgcn_readfirstlane(perm[wv]);
    float o = gat_node(xl, xr, row_start, cnt, csr_src, csr_ea, We, att, bias, d, lane, 1);
    int q = lane >> 4, cc = lane & 15;
    const float* W = (q == 0) ? fWl : (q == 1) ? sWl : (q == 2) ? fWr : sWr;
    const float* B = (q == 0) ? fbl : (q == 1) ? sbl : (q == 2) ? fbr : sbr;
    float a0 = 0.f, a1 = 0.f;
#pragma unroll 8
    for (int k = 0; k < 64; k += 2) {
        a0 += __shfl(o, k) * W[k * 16 + cc];
        a1 += __shfl(o, k + 1) * W[(k + 1) * 16 + cc];
    }
    packed[(size_t)d * 64 + lane] = a0 + a1 + B[cc];
}

// final two H=16,C=1 layers fused: half-wave per dst (0-15 f -> fin, 16-31 s -> mus)
__launch_bounds__(256)
__global__ void k_gat_final(const float* __restrict__ packed,
                            const int* __restrict__ row_start, const int* __restrict__ cnt,
                            const int* __restrict__ csr_src, const float* __restrict__ csr_ea,
                            const int* __restrict__ perm,
                            const float* __restrict__ fWe, const float* __restrict__ sWe,
                            const float* __restrict__ fatt, const float* __restrict__ satt,
                            const float* __restrict__ fbias, const float* __restrict__ sbias,
                            float* __restrict__ fin, float* __restrict__ mus, int n) {
    int hw = (blockIdx.x * blockDim.x + threadIdx.x) >> 5;
    if (hw >= n) return;
    int l = threadIdx.x & 31;
    int hh = l & 15, sel = l >> 4;
    const int d = perm[hw];
    const int p0 = row_start[d], p1 = p0 + cnt[d] + 1;
    const float* We = sel ? sWe : fWe;
    float we0 = We[hh], we1 = We[16 + hh];
    float av = (sel ? satt : fatt)[hh];
    float xrv = packed[(size_t)d * 64 + 32 + sel * 16 + hh];
    int xli = sel * 16 + hh;

    float den0 = 0.f, acc0 = 0.f;
    float den1 = 0.f, acc1 = 0.f;

    auto step = [&](float xv, float2 ea, bool valid, float& den, float& acc) {
        float t = lrelu(xv + xrv + ea.x * we0 + ea.y * we1, 0.2f) * av;
        if (!valid) t = -__builtin_inff();
        float w = __expf(t);
        den += w;
        acc += w * xv;
    };

    for (int p = p0; p < p1; p += 4) {
        int q1 = min(p + 1, p1 - 1), q2 = min(p + 2, p1 - 1), q3 = min(p + 3, p1 - 1);
        int s0 = csr_src[p], s1 = csr_src[q1], s2 = csr_src[q2], s3 = csr_src[q3];
        float2 e0 = *(const float2*)(csr_ea + 2 * (size_t)p);
        float2 e1 = *(const float2*)(csr_ea + 2 * (size_t)q1);
        float2 e2 = *(const float2*)(csr_ea + 2 * (size_t)q2);
        float2 e3 = *(const float2*)(csr_ea + 2 * (size_t)q3);
        float x0 = packed[(size_t)s0 * 64 + xli];
        float x1 = packed[(size_t)s1 * 64 + xli];
        float x2 = packed[(size_t)s2 * 64 + xli];
        float x3 = packed[(size_t)s3 * 64 + xli];
        step(x0, e0, true, den0, acc0);
        step(x1, e1, p + 1 < p1, den1, acc1);
        step(x2, e2, p + 2 < p1, den0, acc0);
        step(x3, e3, p + 3 < p1, den1, acc1);
    }
    float val = (acc0 + acc1) / (den0 + den1);
#pragma unroll
    for (int w = 1; w < 16; w <<= 1) val += __shfl_xor(val, w);
    if ((threadIdx.x & 15) == 0) {
        float o = val * (1.f / 16.f) + (sel ? sbias[0] : fbias[0]);
        if (sel) mus[d] = o; else fin[d] = o;
    }
}

// ---------------- batchnorm stats ----------------

__global__ void k_bnstats(const float* __restrict__ h, double* __restrict__ stats, int n) {
    int c = threadIdx.x & 63;
    int s0 = blockIdx.x * (blockDim.x >> 6) + (threadIdx.x >> 6);
    int ns = gridDim.x * (blockDim.x >> 6);
    double s = 0.0, s2 = 0.0;
    for (int i = s0; i < n; i += ns) {
        float v = h[(size_t)i * 64 + c];
        s += v;
        s2 += (double)v * v;
    }
    atomicAdd(&stats[c], s);
    atomicAdd(&stats[64 + c], s2);
}

// ---------------- graph-level mean over masked nodes ----------------

__global__ void k_sat_acc(const float* __restrict__ fin, const int* __restrict__ mask,
                          const int* __restrict__ batch,
                          float* __restrict__ sums, float* __restrict__ cnts, int n) {
    int i = blockIdx.x * blockDim.x + threadIdx.x;
    int lane = threadIdx.x & 63;
    int g = (i < n) ? batch[i] : -1;
    float c = (i < n && mask[i] == 0) ? 1.f : 0.f;
    float v = (c > 0.f) ? fin[i] : 0.f;
#pragma unroll
    for (int off = 1; off < 64; off <<= 1) {
        float v2 = __shfl_down(v, off);
        float c2 = __shfl_down(c, off);
        int g2 = __shfl_down(g, off);
        if (lane + off < 64 && g2 == g) { v += v2; c += c2; }
    }
    int gprev = __shfl_up(g, 1);
    bool head = (lane == 0) || (gprev != g);
    if (head && g >= 0 && c > 0.f) {
        atomicAdd(&sums[g], v);
        atomicAdd(&cnts[g], c);
    }
}

__global__ void k_sat_fin(const float* __restrict__ sums, const float* __restrict__ cnts,
                          float* __restrict__ out, int g) {
    int i = threadIdx.x;
    if (i < g) out[i] = sums[i] / fmaxf(cnts[i], 1.f);
}

// ---------------- host ----------------

extern "C" void kernel_launch(void* const* d_in, const int* in_sizes, int n_in,
                              void* d_out, int out_size, void* d_ws, size_t ws_size,
                              hipStream_t stream) {
    const float* x = (const float*)d_in[0];
    const float* eat = (const float*)d_in[1];
    const int* ei = (const int*)d_in[2];
    const int* mask = (const int*)d_in[3];
    const int* batch = (const int*)d_in[4];
    const float* g0_Wl = (const float*)d_in[5];
    const float* g0_bl = (const float*)d_in[6];
    const float* g0_Wr = (const float*)d_in[7];
    const float* g0_br = (const float*)d_in[8];
    const float* g0_We = (const float*)d_in[9];
    const float* g0_att = (const float*)d_in[10];
    const float* g0_bias = (const float*)d_in[11];
    const float* bn_g = (const float*)d_in[12];
    const float* bn_b = (const float*)d_in[13];
    const float* m_Wl = (const float*)d_in[14];
    const float* m_bl = (const float*)d_in[15];
    const float* m_Wr = (const float*)d_in[16];
    const float* m_br = (const float*)d_in[17];
    const float* m_We = (const float*)d_in[18];
    const float* m_att = (const float*)d_in[19];
    const float* m_bias = (const float*)d_in[20];
    const float* f_Wl = (const float*)d_in[21];
    const float* f_bl = (const float*)d_in[22];
    const float* f_Wr = (const float*)d_in[23];
    const float* f_br = (const float*)d_in[24];
    const float* f_We = (const float*)d_in[25];
    const float* f_att = (const float*)d_in[26];
    const float* f_bias = (const float*)d_in[27];
    const float* s_Wl = (const float*)d_in[28];
    const float* s_bl = (const float*)d_in[29];
    const float* s_Wr = (const float*)d_in[30];
    const float* s_br = (const float*)d_in[31];
    const float* s_We = (const float*)d_in[32];
    const float* s_att = (const float*)d_in[33];
    const float* s_bias = (const float*)d_in[34];

    const int N = in_sizes[3];
    const int E = in_sizes[1] / 2;
    const int G = out_size - N;
    const int ITER = in_sizes[14] / 4096;
    const int ET = E + N;
    const int* srcp = ei;
    const int* dstp = ei + E;

    char* wsb = (char*)d_ws;
    size_t off = 0;
    auto alloc = [&](size_t b) { void* p = wsb + off; off = (off + b + 255) & ~(size_t)255; return p; };
    int* cnt = (int*)alloc((size_t)N * 4);
    int* cursor = (int*)alloc(256);
    int* hist = (int*)alloc(128 * 4);
    double* stats = (double*)alloc(128 * 8);
    float* sums = (float*)alloc((size_t)G * 4);
    float* cnts = (float*)alloc((size_t)G * 4);
    size_t zero_bytes = off;
    int* rank = (int*)alloc((size_t)E * 4);
    int* row_start = (int*)alloc((size_t)N * 4);
    int* perm = (int*)alloc((size_t)N * 4);
    int* csr_src = (int*)alloc((size_t)ET * 4);
    float* csr_ea = (float*)alloc((size_t)ET * 8);
    float* xlA = (float*)alloc((size_t)N * 256);
    float* xrA = (float*)alloc((size_t)N * 256);
    float* xlB = (float*)alloc((size_t)N * 256);
    float* xrB = (float*)alloc((size_t)N * 256);
    float* hbuf = (float*)alloc((size_t)N * 256);
    float* fin = (float*)alloc((size_t)N * 4);
    (void)ws_size; (void)n_in;

    float* outv = (float*)d_out;  // [0,N) = mus, [N,N+G) = sat

    hipMemsetAsync(d_ws, 0, zero_bytes, stream);
    const int tb = 256;
    const int ggrid = (N * 64 + 255) / 256;
    k_build0<<<(E + N * 64 + tb - 1) / tb, tb, 0, stream>>>(dstp, cnt, rank, E,
                                                            x, g0_Wl, g0_bl, g0_Wr, g0_br,
                                                            xlA, xrA, N);
    k_segoff<<<(N + tb - 1) / tb, tb, 0, stream>>>(cnt, row_start, cursor, N);
    k_hist<<<(N + tb - 1) / tb, tb, 0, stream>>>(cnt, hist, N);
    k_binoff<<<1, 64, 0, stream>>>(hist);
    k_perm<<<(N + tb - 1) / tb, tb, 0, stream>>>(cnt, hist, perm, N);
    k_scatter<<<(E + tb - 1) / tb, tb, 0, stream>>>(srcp, dstp, eat, rank, row_start,
                                                    csr_src, csr_ea, E);
    k_selfloop<<<(N + tb - 1) / tb, tb, 0, stream>>>(row_start, cnt, csr_src, csr_ea, N);

    k_gat<<<ggrid, tb, 0, stream>>>(xlA, xrA, row_start, cnt, csr_src, csr_ea, perm,
                                    g0_We, g0_att, g0_bias, hbuf, N, 0);
    k_bnstats<<<128, 256, 0, stream>>>(hbuf, stats, N);
    k_proj64<<<(N + 127) / 128, 256, 0, stream>>>(hbuf, m_Wl, m_bl, m_Wr, m_br,
                                                  stats, bn_g, bn_b, xlA, xrA, N);

    float* cur_l = xlA; float* cur_r = xrA;
    float* alt_l = xlB; float* alt_r = xrB;
    for (int l = 0; l < ITER; ++l) {
        if (l < ITER - 1) {
            k_gat_proj<<<ggrid, tb, 0, stream>>>(cur_l, cur_r, row_start, cnt, csr_src, csr_ea,
                                                 perm,
                                                 m_We + l * 128, m_att + l * 64, m_bias + l * 64,
                                                 m_Wl + (size_t)(l + 1) * 4096, m_bl + (l + 1) * 64,
                                                 m_Wr + (size_t)(l + 1) * 4096, m_br + (l + 1) * 64,
                                                 alt_l, alt_r, N);
        } else {
            k_gat_projfin<<<ggrid, tb, 0, stream>>>(cur_l, cur_r, row_start, cnt, csr_src, csr_ea,
                                                    perm,
                                                    m_We + l * 128, m_att + l * 64, m_bias + l * 64,
                                                    f_Wl, f_bl, f_Wr, f_br,
                                                    s_Wl, s_bl, s_Wr, s_br,
                                                    alt_l, N);
        }
        float* t;
        t = cur_l; cur_l = alt_l; alt_l = t;
        t = cur_r; cur_r = alt_r; alt_r = t;
    }
    k_gat_final<<<(N * 32 + tb - 1) / tb, tb, 0, stream>>>(cur_l, row_start, cnt, csr_src, csr_ea,
                                                           perm,
                                                           f_We, s_We, f_att, s_att,
                                                           f_bias, s_bias, fin, outv, N);
    k_sat_acc<<<(N + tb - 1) / tb, tb, 0, stream>>>(fin, mask, batch, sums, cnts, N);
    k_sat_fin<<<1, 64, 0, stream>>>(sums, cnts, outv + N, G);
}

// Round 15
// 655.859 us; speedup vs baseline: 1.1968x; 1.1968x over previous
//
#include <hip/hip_runtime.h>

// GATv2 stack on MI355X. fp32 throughout (no fp32 MFMA on CDNA4 -> vector ALU).
// R14: revert R13's degree-sort (k_perm/k_hist atomic serialization cost 136us,
// gat gained exactly 0 -- LPT theory falsified). Back to R12 (best, 649us) plus
// one change: csr entries packed as int4{src, ea.x, ea.y, -} -> one dwordx4
// per edge instead of dword+dwordx2 (halves edge-stream load instructions).

static __device__ __forceinline__ float lrelu(float x, float s) {
    return x > 0.f ? x : s * x;
}

// ---------------- fused degree + proj0 ----------------
__global__ void k_build0(const int* __restrict__ dst, int* __restrict__ cnt,
                         int* __restrict__ rank, int E,
                         const float* __restrict__ x,
                         const float* __restrict__ Wl, const float* __restrict__ bl,
                         const float* __restrict__ Wr, const float* __restrict__ br,
                         float* __restrict__ xl, float* __restrict__ xr, int n) {
    int idx = blockIdx.x * blockDim.x + threadIdx.x;
    if (idx < E) {
        rank[idx] = atomicAdd(&cnt[dst[idx]], 1);
    } else {
        int t = idx - E;
        if (t < n * 64) {
            int i = t >> 6, c = t & 63;
            float x0 = x[2 * i], x1 = x[2 * i + 1];
            xl[t] = x0 * Wl[c] + x1 * Wl[64 + c] + bl[c];
            xr[t] = x0 * Wr[c] + x1 * Wr[64 + c] + br[c];
        }
    }
}

// wave-aggregated segment offset allocation
__global__ void k_segoff(const int* __restrict__ cnt, int* __restrict__ row_start,
                         int* __restrict__ cursor, int n) {
    int i = blockIdx.x * blockDim.x + threadIdx.x;
    int lane = threadIdx.x & 63;
    int v = (i < n) ? cnt[i] + 1 : 0;
    int s = v;
#pragma unroll
    for (int off = 1; off < 64; off <<= 1) {
        int t = __shfl_up(s, off);
        if (lane >= off) s += t;
    }
    int wavetot = __shfl(s, 63);
    int base = 0;
    if (lane == 63) base = atomicAdd(cursor, wavetot);
    base = __shfl(base, 63);
    if (i < n) row_start[i] = base + s - v;
}

// scatter edges into packed CSR: int4{src, bits(ea0), bits(ea1), 0}
__global__ void k_scatter(const int* __restrict__ src, const int* __restrict__ dst,
                          const float* __restrict__ ea, const int* __restrict__ rank,
                          const int* __restrict__ row_start,
                          int4* __restrict__ csr, int E) {
    int e = blockIdx.x * blockDim.x + threadIdx.x;
    if (e >= E) return;
    int pos = row_start[dst[e]] + rank[e];
    float2 a = *(const float2*)(ea + 2 * (size_t)e);
    csr[pos] = make_int4(src[e], __float_as_int(a.x), __float_as_int(a.y), 0);
}

__global__ void k_selfloop(const int* __restrict__ row_start, const int* __restrict__ cnt,
                           int4* __restrict__ csr, int n) {
    int i = blockIdx.x * blockDim.x + threadIdx.x;
    if (i >= n) return;
    int p0 = row_start[i], deg = cnt[i];
    float s0 = 0.f, s1 = 0.f;
    for (int p = p0; p < p0 + deg; ++p) {
        int4 v = csr[p];
        s0 += __int_as_float(v.y);
        s1 += __int_as_float(v.z);
    }
    float c = fmaxf((float)deg, 1.f);
    csr[p0 + deg] = make_int4(i, __float_as_int(s0 / c), __float_as_int(s1 / c), 0);
}

// ---------------- layer-0 projection with fused BN (reads hbuf) ----------------
__launch_bounds__(256)
__global__ void k_proj64(const float* __restrict__ h,
                         const float* __restrict__ Wl, const float* __restrict__ bl,
                         const float* __restrict__ Wr, const float* __restrict__ br,
                         const double* __restrict__ stats,
                         const float* __restrict__ bng, const float* __restrict__ bnb,
                         float* __restrict__ xl, float* __restrict__ xr, int n) {
    __shared__ float wsl[4096], wsr[4096], bna[64], bnbb[64];
    int t = threadIdx.x;
    for (int i = t; i < 4096; i += 256) { wsl[i] = Wl[i]; wsr[i] = Wr[i]; }
    if (t < 64) {
        double mu = stats[t] / n;
        double var = stats[64 + t] / n - mu * mu;
        float rs = (float)(1.0 / sqrt(var + 1e-5));
        float a = rs * bng[t];
        bna[t] = a;
        bnbb[t] = bnb[t] - (float)mu * a;
    }
    __syncthreads();
    int rg = t >> 2, cg4 = (t & 3) << 4;
    int r0 = blockIdx.x * 128 + rg * 2;
    float accl[2][16], accr[2][16];
#pragma unroll
    for (int r = 0; r < 2; ++r)
#pragma unroll
        for (int j = 0; j < 16; ++j) { accl[r][j] = 0.f; accr[r][j] = 0.f; }
    for (int k0 = 0; k0 < 64; k0 += 4) {
        float hk[2][4];
#pragma unroll
        for (int r = 0; r < 2; ++r) {
            int gr = r0 + r;
            float4 v = (gr < n) ? *(const float4*)(h + (size_t)gr * 64 + k0)
                                : make_float4(0.f, 0.f, 0.f, 0.f);
            hk[r][0] = v.x; hk[r][1] = v.y; hk[r][2] = v.z; hk[r][3] = v.w;
#pragma unroll
            for (int kk = 0; kk < 4; ++kk)
                hk[r][kk] = lrelu(hk[r][kk] * bna[k0 + kk] + bnbb[k0 + kk], 0.01f);
        }
#pragma unroll
        for (int kk = 0; kk < 4; ++kk) {
            const float* wl = wsl + (k0 + kk) * 64 + cg4;
            const float* wr = wsr + (k0 + kk) * 64 + cg4;
#pragma unroll
            for (int r = 0; r < 2; ++r)
#pragma unroll
                for (int j = 0; j < 16; ++j) {
                    accl[r][j] += hk[r][kk] * wl[j];
                    accr[r][j] += hk[r][kk] * wr[j];
                }
        }
    }
#pragma unroll
    for (int r = 0; r < 2; ++r) {
        int gr = r0 + r;
        if (gr < n) {
            float* ol = xl + (size_t)gr * 64 + cg4;
            float* orr = xr + (size_t)gr * 64 + cg4;
#pragma unroll
            for (int j = 0; j < 16; ++j) {
                ol[j] = accl[r][j] + bl[cg4 + j];
                orr[j] = accr[r][j] + br[cg4 + j];
            }
        }
    }
}

// ---------------- gat node body (shared) ----------------
// plain exp-sum softmax: w = exp(logit), pad edges give exp(-inf)=0
__device__ __forceinline__ float gat_node(const float* __restrict__ xl,
                                          const float* __restrict__ xr,
                                          const int* __restrict__ row_start,
                                          const int* __restrict__ cnt,
                                          const int4* __restrict__ csr,
                                          const float* __restrict__ We,
                                          const float* __restrict__ att,
                                          const float* __restrict__ bias,
                                          int d, int lane, int relu) {
    const int p0 = __builtin_amdgcn_readfirstlane(row_start[d]);
    const int p1 = p0 + __builtin_amdgcn_readfirstlane(cnt[d]) + 1;
    const float we0 = We[lane], we1 = We[64 + lane];
    const float av = att[lane];
    const float xrv = xr[(size_t)d * 64 + lane];

    float den0 = 0.f, acc0 = 0.f;
    float den1 = 0.f, acc1 = 0.f;

    auto step = [&](float xv, float e0, float e1, bool valid, float& den, float& acc) {
        float tv = lrelu(xv + xrv + e0 * we0 + e1 * we1, 0.2f) * av;
        tv += __shfl_xor(tv, 1);
        tv += __shfl_xor(tv, 2);
        if (!valid) tv = -__builtin_inff();
        float w = __expf(tv);
        den += w;
        acc += w * xv;
    };

    for (int p = p0; p < p1; p += 4) {
        int q1 = min(p + 1, p1 - 1), q2 = min(p + 2, p1 - 1), q3 = min(p + 3, p1 - 1);
        int4 c0 = csr[p], c1 = csr[q1], c2 = csr[q2], c3 = csr[q3];
        float x0 = xl[(size_t)c0.x * 64 + lane];
        float x1 = xl[(size_t)c1.x * 64 + lane];
        float x2 = xl[(size_t)c2.x * 64 + lane];
        float x3 = xl[(size_t)c3.x * 64 + lane];
        step(x0, __int_as_float(c0.y), __int_as_float(c0.z), true, den0, acc0);
        step(x1, __int_as_float(c1.y), __int_as_float(c1.z), p + 1 < p1, den1, acc1);
        step(x2, __int_as_float(c2.y), __int_as_float(c2.z), p + 2 < p1, den0, acc0);
        step(x3, __int_as_float(c3.y), __int_as_float(c3.z), p + 3 < p1, den1, acc1);
    }
    float o = (acc0 + acc1) / (den0 + den1) + bias[lane];
    if (relu) o = lrelu(o, 0.01f);
    return o;
}

// plain gat (layer 0 -> hbuf, no relu)
__launch_bounds__(256)
__global__ void k_gat(const float* __restrict__ xl, const float* __restrict__ xr,
                      const int* __restrict__ row_start, const int* __restrict__ cnt,
                      const int4* __restrict__ csr,
                      const float* __restrict__ We, const float* __restrict__ att,
                      const float* __restrict__ bias,
                      float* __restrict__ out, int n, int relu) {
    int wave = (blockIdx.x * blockDim.x + threadIdx.x) >> 6;
    int lane = threadIdx.x & 63;
    if (wave >= n) return;
    float o = gat_node(xl, xr, row_start, cnt, csr, We, att, bias, wave, lane, relu);
    out[(size_t)wave * 64 + lane] = o;
}

// gat + fused next-layer dual projection epilogue (per-wave, L1-resident weights)
__launch_bounds__(256)
__global__ void k_gat_proj(const float* __restrict__ xl, const float* __restrict__ xr,
                           const int* __restrict__ row_start, const int* __restrict__ cnt,
                           const int4* __restrict__ csr,
                           const float* __restrict__ We, const float* __restrict__ att,
                           const float* __restrict__ bias,
                           const float* __restrict__ Wnl, const float* __restrict__ bnl,
                           const float* __restrict__ Wnr, const float* __restrict__ bnr,
                           float* __restrict__ xl_out, float* __restrict__ xr_out, int n) {
    int wave = (blockIdx.x * blockDim.x + threadIdx.x) >> 6;
    int lane = threadIdx.x & 63;
    if (wave >= n) return;
    const int d = wave;
    float o = gat_node(xl, xr, row_start, cnt, csr, We, att, bias, d, lane, 1);
    float a0 = 0.f, a1 = 0.f, b0 = 0.f, b1 = 0.f;
#pragma unroll 8
    for (int k = 0; k < 64; k += 2) {
        float h0 = __shfl(o, k);
        float h1 = __shfl(o, k + 1);
        a0 += h0 * Wnl[k * 64 + lane];
        a1 += h1 * Wnl[(k + 1) * 64 + lane];
        b0 += h0 * Wnr[k * 64 + lane];
        b1 += h1 * Wnr[(k + 1) * 64 + lane];
    }
    xl_out[(size_t)d * 64 + lane] = a0 + a1 + bnl[lane];
    xr_out[(size_t)d * 64 + lane] = b0 + b1 + bnr[lane];
}

// gat + fused FINAL packed projection epilogue
// packed[d] = [f_xl(16) | s_xl(16) | f_xr(16) | s_xr(16)]
__launch_bounds__(256)
__global__ void k_gat_projfin(const float* __restrict__ xl, const float* __restrict__ xr,
                              const int* __restrict__ row_start, const int* __restrict__ cnt,
                              const int4* __restrict__ csr,
                              const float* __restrict__ We, const float* __restrict__ att,
                              const float* __restrict__ bias,
                              const float* __restrict__ fWl, const float* __restrict__ fbl,
                              const float* __restrict__ fWr, const float* __restrict__ fbr,
                              const float* __restrict__ sWl, const float* __restrict__ sbl,
                              const float* __restrict__ sWr, const float* __restrict__ sbr,
                              float* __restrict__ packed, int n) {
    int wave = (blockIdx.x * blockDim.x + threadIdx.x) >> 6;
    int lane = threadIdx.x & 63;
    if (wave >= n) return;
    const int d = wave;
    float o = gat_node(xl, xr, row_start, cnt, csr, We, att, bias, d, lane, 1);
    int q = lane >> 4, cc = lane & 15;
    const float* W = (q == 0) ? fWl : (q == 1) ? sWl : (q == 2) ? fWr : sWr;
    const float* B = (q == 0) ? fbl : (q == 1) ? sbl : (q == 2) ? fbr : sbr;
    float a0 = 0.f, a1 = 0.f;
#pragma unroll 8
    for (int k = 0; k < 64; k += 2) {
        a0 += __shfl(o, k) * W[k * 16 + cc];
        a1 += __shfl(o, k + 1) * W[(k + 1) * 16 + cc];
    }
    packed[(size_t)d * 64 + lane] = a0 + a1 + B[cc];
}

// final two H=16,C=1 layers fused: half-wave per dst (0-15 f -> fin, 16-31 s -> mus)
__launch_bounds__(256)
__global__ void k_gat_final(const float* __restrict__ packed,
                            const int* __restrict__ row_start, const int* __restrict__ cnt,
                            const int4* __restrict__ csr,
                            const float* __restrict__ fWe, const float* __restrict__ sWe,
                            const float* __restrict__ fatt, const float* __restrict__ satt,
                            const float* __restrict__ fbias, const float* __restrict__ sbias,
                            float* __restrict__ fin, float* __restrict__ mus, int n) {
    int hw = (blockIdx.x * blockDim.x + threadIdx.x) >> 5;
    if (hw >= n) return;
    int l = threadIdx.x & 31;
    int hh = l & 15, sel = l >> 4;
    const int d = hw;
    const int p0 = row_start[d], p1 = p0 + cnt[d] + 1;
    const float* We = sel ? sWe : fWe;
    float we0 = We[hh], we1 = We[16 + hh];
    float av = (sel ? satt : fatt)[hh];
    float xrv = packed[(size_t)d * 64 + 32 + sel * 16 + hh];
    int xli = sel * 16 + hh;

    float den0 = 0.f, acc0 = 0.f;
    float den1 = 0.f, acc1 = 0.f;

    auto step = [&](float xv, float e0, float e1, bool valid, float& den, float& acc) {
        float t = lrelu(xv + xrv + e0 * we0 + e1 * we1, 0.2f) * av;
        if (!valid) t = -__builtin_inff();
        float w = __expf(t);
        den += w;
        acc += w * xv;
    };

    for (int p = p0; p < p1; p += 4) {
        int q1 = min(p + 1, p1 - 1), q2 = min(p + 2, p1 - 1), q3 = min(p + 3, p1 - 1);
        int4 c0 = csr[p], c1 = csr[q1], c2 = csr[q2], c3 = csr[q3];
        float x0 = packed[(size_t)c0.x * 64 + xli];
        float x1 = packed[(size_t)c1.x * 64 + xli];
        float x2 = packed[(size_t)c2.x * 64 + xli];
        float x3 = packed[(size_t)c3.x * 64 + xli];
        step(x0, __int_as_float(c0.y), __int_as_float(c0.z), true, den0, acc0);
        step(x1, __int_as_float(c1.y), __int_as_float(c1.z), p + 1 < p1, den1, acc1);
        step(x2, __int_as_float(c2.y), __int_as_float(c2.z), p + 2 < p1, den0, acc0);
        step(x3, __int_as_float(c3.y), __int_as_float(c3.z), p + 3 < p1, den1, acc1);
    }
    float val = (acc0 + acc1) / (den0 + den1);
#pragma unroll
    for (int w = 1; w < 16; w <<= 1) val += __shfl_xor(val, w);
    if ((threadIdx.x & 15) == 0) {
        float o = val * (1.f / 16.f) + (sel ? sbias[0] : fbias[0]);
        if (sel) mus[d] = o; else fin[d] = o;
    }
}

// ---------------- batchnorm stats ----------------

__global__ void k_bnstats(const float* __restrict__ h, double* __restrict__ stats, int n) {
    int c = threadIdx.x & 63;
    int s0 = blockIdx.x * (blockDim.x >> 6) + (threadIdx.x >> 6);
    int ns = gridDim.x * (blockDim.x >> 6);
    double s = 0.0, s2 = 0.0;
    for (int i = s0; i < n; i += ns) {
        float v = h[(size_t)i * 64 + c];
        s += v;
        s2 += (double)v * v;
    }
    atomicAdd(&stats[c], s);
    atomicAdd(&stats[64 + c], s2);
}

// ---------------- graph-level mean over masked nodes ----------------

__global__ void k_sat_acc(const float* __restrict__ fin, const int* __restrict__ mask,
                          const int* __restrict__ batch,
                          float* __restrict__ sums, float* __restrict__ cnts, int n) {
    int i = blockIdx.x * blockDim.x + threadIdx.x;
    int lane = threadIdx.x & 63;
    int g = (i < n) ? batch[i] : -1;
    float c = (i < n && mask[i] == 0) ? 1.f : 0.f;
    float v = (c > 0.f) ? fin[i] : 0.f;
#pragma unroll
    for (int off = 1; off < 64; off <<= 1) {
        float v2 = __shfl_down(v, off);
        float c2 = __shfl_down(c, off);
        int g2 = __shfl_down(g, off);
        if (lane + off < 64 && g2 == g) { v += v2; c += c2; }
    }
    int gprev = __shfl_up(g, 1);
    bool head = (lane == 0) || (gprev != g);
    if (head && g >= 0 && c > 0.f) {
        atomicAdd(&sums[g], v);
        atomicAdd(&cnts[g], c);
    }
}

__global__ void k_sat_fin(const float* __restrict__ sums, const float* __restrict__ cnts,
                          float* __restrict__ out, int g) {
    int i = threadIdx.x;
    if (i < g) out[i] = sums[i] / fmaxf(cnts[i], 1.f);
}

// ---------------- host ----------------

extern "C" void kernel_launch(void* const* d_in, const int* in_sizes, int n_in,
                              void* d_out, int out_size, void* d_ws, size_t ws_size,
                              hipStream_t stream) {
    const float* x = (const float*)d_in[0];
    const float* eat = (const float*)d_in[1];
    const int* ei = (const int*)d_in[2];
    const int* mask = (const int*)d_in[3];
    const int* batch = (const int*)d_in[4];
    const float* g0_Wl = (const float*)d_in[5];
    const float* g0_bl = (const float*)d_in[6];
    const float* g0_Wr = (const float*)d_in[7];
    const float* g0_br = (const float*)d_in[8];
    const float* g0_We = (const float*)d_in[9];
    const float* g0_att = (const float*)d_in[10];
    const float* g0_bias = (const float*)d_in[11];
    const float* bn_g = (const float*)d_in[12];
    const float* bn_b = (const float*)d_in[13];
    const float* m_Wl = (const float*)d_in[14];
    const float* m_bl = (const float*)d_in[15];
    const float* m_Wr = (const float*)d_in[16];
    const float* m_br = (const float*)d_in[17];
    const float* m_We = (const float*)d_in[18];
    const float* m_att = (const float*)d_in[19];
    const float* m_bias = (const float*)d_in[20];
    const float* f_Wl = (const float*)d_in[21];
    const float* f_bl = (const float*)d_in[22];
    const float* f_Wr = (const float*)d_in[23];
    const float* f_br = (const float*)d_in[24];
    const float* f_We = (const float*)d_in[25];
    const float* f_att = (const float*)d_in[26];
    const float* f_bias = (const float*)d_in[27];
    const float* s_Wl = (const float*)d_in[28];
    const float* s_bl = (const float*)d_in[29];
    const float* s_Wr = (const float*)d_in[30];
    const float* s_br = (const float*)d_in[31];
    const float* s_We = (const float*)d_in[32];
    const float* s_att = (const float*)d_in[33];
    const float* s_bias = (const float*)d_in[34];

    const int N = in_sizes[3];
    const int E = in_sizes[1] / 2;
    const int G = out_size - N;
    const int ITER = in_sizes[14] / 4096;
    const int ET = E + N;
    const int* srcp = ei;
    const int* dstp = ei + E;

    char* wsb = (char*)d_ws;
    size_t off = 0;
    auto alloc = [&](size_t b) { void* p = wsb + off; off = (off + b + 255) & ~(size_t)255; return p; };
    int* cnt = (int*)alloc((size_t)N * 4);
    int* cursor = (int*)alloc(256);
    double* stats = (double*)alloc(128 * 8);
    float* sums = (float*)alloc((size_t)G * 4);
    float* cnts = (float*)alloc((size_t)G * 4);
    size_t zero_bytes = off;
    int* rank = (int*)alloc((size_t)E * 4);
    int* row_start = (int*)alloc((size_t)N * 4);
    int4* csr = (int4*)alloc((size_t)ET * 16);
    float* xlA = (float*)alloc((size_t)N * 256);
    float* xrA = (float*)alloc((size_t)N * 256);
    float* xlB = (float*)alloc((size_t)N * 256);
    float* xrB = (float*)alloc((size_t)N * 256);
    float* hbuf = (float*)alloc((size_t)N * 256);
    float* fin = (float*)alloc((size_t)N * 4);
    (void)ws_size; (void)n_in;

    float* outv = (float*)d_out;  // [0,N) = mus, [N,N+G) = sat

    hipMemsetAsync(d_ws, 0, zero_bytes, stream);
    const int tb = 256;
    const int ggrid = (N * 64 + 255) / 256;
    k_build0<<<(E + N * 64 + tb - 1) / tb, tb, 0, stream>>>(dstp, cnt, rank, E,
                                                            x, g0_Wl, g0_bl, g0_Wr, g0_br,
                                                            xlA, xrA, N);
    k_segoff<<<(N + tb - 1) / tb, tb, 0, stream>>>(cnt, row_start, cursor, N);
    k_scatter<<<(E + tb - 1) / tb, tb, 0, stream>>>(srcp, dstp, eat, rank, row_start, csr, E);
    k_selfloop<<<(N + tb - 1) / tb, tb, 0, stream>>>(row_start, cnt, csr, N);

    k_gat<<<ggrid, tb, 0, stream>>>(xlA, xrA, row_start, cnt, csr,
                                    g0_We, g0_att, g0_bias, hbuf, N, 0);
    k_bnstats<<<128, 256, 0, stream>>>(hbuf, stats, N);
    k_proj64<<<(N + 127) / 128, 256, 0, stream>>>(hbuf, m_Wl, m_bl, m_Wr, m_br,
                                                  stats, bn_g, bn_b, xlA, xrA, N);

    float* cur_l = xlA; float* cur_r = xrA;
    float* alt_l = xlB; float* alt_r = xrB;
    for (int l = 0; l < ITER; ++l) {
        if (l < ITER - 1) {
            k_gat_proj<<<ggrid, tb, 0, stream>>>(cur_l, cur_r, row_start, cnt, csr,
                                                 m_We + l * 128, m_att + l * 64, m_bias + l * 64,
                                                 m_Wl + (size_t)(l + 1) * 4096, m_bl + (l + 1) * 64,
                                                 m_Wr + (size_t)(l + 1) * 4096, m_br + (l + 1) * 64,
                                                 alt_l, alt_r, N);
        } else {
            k_gat_projfin<<<ggrid, tb, 0, stream>>>(cur_l, cur_r, row_start, cnt, csr,
                                                    m_We + l * 128, m_att + l * 64, m_bias + l * 64,
                                                    f_Wl, f_bl, f_Wr, f_br,
                                                    s_Wl, s_bl, s_Wr, s_br,
                                                    alt_l, N);
        }
        float* t;
        t = cur_l; cur_l = alt_l; alt_l = t;
        t = cur_r; cur_r = alt_r; alt_r = t;
    }
    k_gat_final<<<(N * 32 + tb - 1) / tb, tb, 0, stream>>>(cur_l, row_start, cnt, csr,
                                                           f_We, s_We, f_att, s_att,
                                                           f_bias, s_bias, fin, outv, N);
    k_sat_acc<<<(N + tb - 1) / tb, tb, 0, stream>>>(fin, mask, batch, sums, cnts, N);
    k_sat_fin<<<1, 64, 0, stream>>>(sums, cnts, outv + N, G);
}

// Round 16
// 645.365 us; speedup vs baseline: 1.2162x; 1.0163x over previous
//
#include <hip/hip_runtime.h>

// GATv2 stack on MI355X. fp32 throughout (no fp32 MFMA on CDNA4 -> vector ALU).
// R15: R12 base (best, 649us; R14's int4 packing reverted - it inflated the
// edge stream 25% for nothing). Change: self-loop inlined into the gat loop
// (wave accumulates masked ea-sums while iterating its segment, then performs
// the self edge with ea = sum/deg) -- deletes the k_selfloop dispatch+gap, the
// segment re-read, and the +1 slot in every CSR segment.

static __device__ __forceinline__ float lrelu(float x, float s) {
    return x > 0.f ? x : s * x;
}

// ---------------- fused degree + proj0 ----------------
__global__ void k_build0(const int* __restrict__ dst, int* __restrict__ cnt,
                         int* __restrict__ rank, int E,
                         const float* __restrict__ x,
                         const float* __restrict__ Wl, const float* __restrict__ bl,
                         const float* __restrict__ Wr, const float* __restrict__ br,
                         float* __restrict__ xl, float* __restrict__ xr, int n) {
    int idx = blockIdx.x * blockDim.x + threadIdx.x;
    if (idx < E) {
        rank[idx] = atomicAdd(&cnt[dst[idx]], 1);
    } else {
        int t = idx - E;
        if (t < n * 64) {
            int i = t >> 6, c = t & 63;
            float x0 = x[2 * i], x1 = x[2 * i + 1];
            xl[t] = x0 * Wl[c] + x1 * Wl[64 + c] + bl[c];
            xr[t] = x0 * Wr[c] + x1 * Wr[64 + c] + br[c];
        }
    }
}

// wave-aggregated segment offset allocation (exactly cnt[i] slots per node)
__global__ void k_segoff(const int* __restrict__ cnt, int* __restrict__ row_start,
                         int* __restrict__ cursor, int n) {
    int i = blockIdx.x * blockDim.x + threadIdx.x;
    int lane = threadIdx.x & 63;
    int v = (i < n) ? cnt[i] : 0;
    int s = v;
#pragma unroll
    for (int off = 1; off < 64; off <<= 1) {
        int t = __shfl_up(s, off);
        if (lane >= off) s += t;
    }
    int wavetot = __shfl(s, 63);
    int base = 0;
    if (lane == 63) base = atomicAdd(cursor, wavetot);
    base = __shfl(base, 63);
    if (i < n) row_start[i] = base + s - v;
}

__global__ void k_scatter(const int* __restrict__ src, const int* __restrict__ dst,
                          const float* __restrict__ ea, const int* __restrict__ rank,
                          const int* __restrict__ row_start,
                          int* __restrict__ csr_src, float* __restrict__ csr_ea, int E) {
    int e = blockIdx.x * blockDim.x + threadIdx.x;
    if (e >= E) return;
    int pos = row_start[dst[e]] + rank[e];
    csr_src[pos] = src[e];
    *(float2*)(csr_ea + 2 * (size_t)pos) = *(const float2*)(ea + 2 * (size_t)e);
}

// ---------------- layer-0 projection with fused BN (reads hbuf) ----------------
__launch_bounds__(256)
__global__ void k_proj64(const float* __restrict__ h,
                         const float* __restrict__ Wl, const float* __restrict__ bl,
                         const float* __restrict__ Wr, const float* __restrict__ br,
                         const double* __restrict__ stats,
                         const float* __restrict__ bng, const float* __restrict__ bnb,
                         float* __restrict__ xl, float* __restrict__ xr, int n) {
    __shared__ float wsl[4096], wsr[4096], bna[64], bnbb[64];
    int t = threadIdx.x;
    for (int i = t; i < 4096; i += 256) { wsl[i] = Wl[i]; wsr[i] = Wr[i]; }
    if (t < 64) {
        double mu = stats[t] / n;
        double var = stats[64 + t] / n - mu * mu;
        float rs = (float)(1.0 / sqrt(var + 1e-5));
        float a = rs * bng[t];
        bna[t] = a;
        bnbb[t] = bnb[t] - (float)mu * a;
    }
    __syncthreads();
    int rg = t >> 2, cg4 = (t & 3) << 4;
    int r0 = blockIdx.x * 128 + rg * 2;
    float accl[2][16], accr[2][16];
#pragma unroll
    for (int r = 0; r < 2; ++r)
#pragma unroll
        for (int j = 0; j < 16; ++j) { accl[r][j] = 0.f; accr[r][j] = 0.f; }
    for (int k0 = 0; k0 < 64; k0 += 4) {
        float hk[2][4];
#pragma unroll
        for (int r = 0; r < 2; ++r) {
            int gr = r0 + r;
            float4 v = (gr < n) ? *(const float4*)(h + (size_t)gr * 64 + k0)
                                : make_float4(0.f, 0.f, 0.f, 0.f);
            hk[r][0] = v.x; hk[r][1] = v.y; hk[r][2] = v.z; hk[r][3] = v.w;
#pragma unroll
            for (int kk = 0; kk < 4; ++kk)
                hk[r][kk] = lrelu(hk[r][kk] * bna[k0 + kk] + bnbb[k0 + kk], 0.01f);
        }
#pragma unroll
        for (int kk = 0; kk < 4; ++kk) {
            const float* wl = wsl + (k0 + kk) * 64 + cg4;
            const float* wr = wsr + (k0 + kk) * 64 + cg4;
#pragma unroll
            for (int r = 0; r < 2; ++r)
#pragma unroll
                for (int j = 0; j < 16; ++j) {
                    accl[r][j] += hk[r][kk] * wl[j];
                    accr[r][j] += hk[r][kk] * wr[j];
                }
        }
    }
#pragma unroll
    for (int r = 0; r < 2; ++r) {
        int gr = r0 + r;
        if (gr < n) {
            float* ol = xl + (size_t)gr * 64 + cg4;
            float* orr = xr + (size_t)gr * 64 + cg4;
#pragma unroll
            for (int j = 0; j < 16; ++j) {
                ol[j] = accl[r][j] + bl[cg4 + j];
                orr[j] = accr[r][j] + br[cg4 + j];
            }
        }
    }
}

// ---------------- gat node body (shared) ----------------
// plain exp-sum softmax; self-loop computed inline (ea = masked segment mean)
__device__ __forceinline__ float gat_node(const float* __restrict__ xl,
                                          const float* __restrict__ xr,
                                          const int* __restrict__ row_start,
                                          const int* __restrict__ cnt,
                                          const int* __restrict__ csr_src,
                                          const float* __restrict__ csr_ea,
                                          const float* __restrict__ We,
                                          const float* __restrict__ att,
                                          const float* __restrict__ bias,
                                          int d, int lane, int relu) {
    const int p0 = __builtin_amdgcn_readfirstlane(row_start[d]);
    const int deg = __builtin_amdgcn_readfirstlane(cnt[d]);
    const int p1 = p0 + deg;
    const float we0 = We[lane], we1 = We[64 + lane];
    const float av = att[lane];
    const float xrv = xr[(size_t)d * 64 + lane];

    float den0 = 0.f, acc0 = 0.f;
    float den1 = 0.f, acc1 = 0.f;
    float s0 = 0.f, s1 = 0.f;  // masked ea sums for the self-loop attr

    auto step = [&](float xv, float2 ea, bool valid, float& den, float& acc) {
        float vm = valid ? 1.f : 0.f;
        s0 = fmaf(vm, ea.x, s0);
        s1 = fmaf(vm, ea.y, s1);
        float tv = lrelu(xv + xrv + ea.x * we0 + ea.y * we1, 0.2f) * av;
        tv += __shfl_xor(tv, 1);
        tv += __shfl_xor(tv, 2);
        if (!valid) tv = -__builtin_inff();
        float w = __expf(tv);
        den += w;
        acc += w * xv;
    };

    for (int p = p0; p < p1; p += 4) {
        int q1 = min(p + 1, p1 - 1), q2 = min(p + 2, p1 - 1), q3 = min(p + 3, p1 - 1);
        int e0s = csr_src[p], e1s = csr_src[q1], e2s = csr_src[q2], e3s = csr_src[q3];
        float2 e0 = *(const float2*)(csr_ea + 2 * (size_t)p);
        float2 e1 = *(const float2*)(csr_ea + 2 * (size_t)q1);
        float2 e2 = *(const float2*)(csr_ea + 2 * (size_t)q2);
        float2 e3 = *(const float2*)(csr_ea + 2 * (size_t)q3);
        float x0 = xl[(size_t)e0s * 64 + lane];
        float x1 = xl[(size_t)e1s * 64 + lane];
        float x2 = xl[(size_t)e2s * 64 + lane];
        float x3 = xl[(size_t)e3s * 64 + lane];
        step(x0, e0, true, den0, acc0);
        step(x1, e1, p + 1 < p1, den1, acc1);
        step(x2, e2, p + 2 < p1, den0, acc0);
        step(x3, e3, p + 3 < p1, den1, acc1);
    }
    // self-loop: attr = segment mean, xv = own features
    {
        float c = fmaxf((float)deg, 1.f);
        float se0 = s0 / c, se1 = s1 / c;
        float xv = xl[(size_t)d * 64 + lane];
        float tv = lrelu(xv + xrv + se0 * we0 + se1 * we1, 0.2f) * av;
        tv += __shfl_xor(tv, 1);
        tv += __shfl_xor(tv, 2);
        float w = __expf(tv);
        den0 += w;
        acc0 += w * xv;
    }
    float o = (acc0 + acc1) / (den0 + den1) + bias[lane];
    if (relu) o = lrelu(o, 0.01f);
    return o;
}

// plain gat (layer 0 -> hbuf, no relu)
__launch_bounds__(256)
__global__ void k_gat(const float* __restrict__ xl, const float* __restrict__ xr,
                      const int* __restrict__ row_start, const int* __restrict__ cnt,
                      const int* __restrict__ csr_src, const float* __restrict__ csr_ea,
                      const float* __restrict__ We, const float* __restrict__ att,
                      const float* __restrict__ bias,
                      float* __restrict__ out, int n, int relu) {
    int wave = (blockIdx.x * blockDim.x + threadIdx.x) >> 6;
    int lane = threadIdx.x & 63;
    if (wave >= n) return;
    float o = gat_node(xl, xr, row_start, cnt, csr_src, csr_ea, We, att, bias, wave, lane, relu);
    out[(size_t)wave * 64 + lane] = o;
}

// gat + fused next-layer dual projection epilogue (per-wave, L1-resident weights)
__launch_bounds__(256)
__global__ void k_gat_proj(const float* __restrict__ xl, const float* __restrict__ xr,
                           const int* __restrict__ row_start, const int* __restrict__ cnt,
                           const int* __restrict__ csr_src, const float* __restrict__ csr_ea,
                           const float* __restrict__ We, const float* __restrict__ att,
                           const float* __restrict__ bias,
                           const float* __restrict__ Wnl, const float* __restrict__ bnl,
                           const float* __restrict__ Wnr, const float* __restrict__ bnr,
                           float* __restrict__ xl_out, float* __restrict__ xr_out, int n) {
    int wave = (blockIdx.x * blockDim.x + threadIdx.x) >> 6;
    int lane = threadIdx.x & 63;
    if (wave >= n) return;
    const int d = wave;
    float o = gat_node(xl, xr, row_start, cnt, csr_src, csr_ea, We, att, bias, d, lane, 1);
    float a0 = 0.f, a1 = 0.f, b0 = 0.f, b1 = 0.f;
#pragma unroll 8
    for (int k = 0; k < 64; k += 2) {
        float h0 = __shfl(o, k);
        float h1 = __shfl(o, k + 1);
        a0 += h0 * Wnl[k * 64 + lane];
        a1 += h1 * Wnl[(k + 1) * 64 + lane];
        b0 += h0 * Wnr[k * 64 + lane];
        b1 += h1 * Wnr[(k + 1) * 64 + lane];
    }
    xl_out[(size_t)d * 64 + lane] = a0 + a1 + bnl[lane];
    xr_out[(size_t)d * 64 + lane] = b0 + b1 + bnr[lane];
}

// gat + fused FINAL packed projection epilogue
// packed[d] = [f_xl(16) | s_xl(16) | f_xr(16) | s_xr(16)]
__launch_bounds__(256)
__global__ void k_gat_projfin(const float* __restrict__ xl, const float* __restrict__ xr,
                              const int* __restrict__ row_start, const int* __restrict__ cnt,
                              const int* __restrict__ csr_src, const float* __restrict__ csr_ea,
                              const float* __restrict__ We, const float* __restrict__ att,
                              const float* __restrict__ bias,
                              const float* __restrict__ fWl, const float* __restrict__ fbl,
                              const float* __restrict__ fWr, const float* __restrict__ fbr,
                              const float* __restrict__ sWl, const float* __restrict__ sbl,
                              const float* __restrict__ sWr, const float* __restrict__ sbr,
                              float* __restrict__ packed, int n) {
    int wave = (blockIdx.x * blockDim.x + threadIdx.x) >> 6;
    int lane = threadIdx.x & 63;
    if (wave >= n) return;
    const int d = wave;
    float o = gat_node(xl, xr, row_start, cnt, csr_src, csr_ea, We, att, bias, d, lane, 1);
    int q = lane >> 4, cc = lane & 15;
    const float* W = (q == 0) ? fWl : (q == 1) ? sWl : (q == 2) ? fWr : sWr;
    const float* B = (q == 0) ? fbl : (q == 1) ? sbl : (q == 2) ? fbr : sbr;
    float a0 = 0.f, a1 = 0.f;
#pragma unroll 8
    for (int k = 0; k < 64; k += 2) {
        a0 += __shfl(o, k) * W[k * 16 + cc];
        a1 += __shfl(o, k + 1) * W[(k + 1) * 16 + cc];
    }
    packed[(size_t)d * 64 + lane] = a0 + a1 + B[cc];
}

// final two H=16,C=1 layers fused: half-wave per dst (0-15 f -> fin, 16-31 s -> mus)
__launch_bounds__(256)
__global__ void k_gat_final(const float* __restrict__ packed,
                            const int* __restrict__ row_start, const int* __restrict__ cnt,
                            const int* __restrict__ csr_src, const float* __restrict__ csr_ea,
                            const float* __restrict__ fWe, const float* __restrict__ sWe,
                            const float* __restrict__ fatt, const float* __restrict__ satt,
                            const float* __restrict__ fbias, const float* __restrict__ sbias,
                            float* __restrict__ fin, float* __restrict__ mus, int n) {
    int hw = (blockIdx.x * blockDim.x + threadIdx.x) >> 5;
    if (hw >= n) return;
    int l = threadIdx.x & 31;
    int hh = l & 15, sel = l >> 4;
    const int d = hw;
    const int p0 = row_start[d], deg = cnt[d], p1 = p0 + deg;
    const float* We = sel ? sWe : fWe;
    float we0 = We[hh], we1 = We[16 + hh];
    float av = (sel ? satt : fatt)[hh];
    float xrv = packed[(size_t)d * 64 + 32 + sel * 16 + hh];
    int xli = sel * 16 + hh;

    float den0 = 0.f, acc0 = 0.f;
    float den1 = 0.f, acc1 = 0.f;
    float s0 = 0.f, s1 = 0.f;

    auto step = [&](float xv, float2 ea, bool valid, float& den, float& acc) {
        float vm = valid ? 1.f : 0.f;
        s0 = fmaf(vm, ea.x, s0);
        s1 = fmaf(vm, ea.y, s1);
        float t = lrelu(xv + xrv + ea.x * we0 + ea.y * we1, 0.2f) * av;
        if (!valid) t = -__builtin_inff();
        float w = __expf(t);
        den += w;
        acc += w * xv;
    };

    for (int p = p0; p < p1; p += 4) {
        int q1 = min(p + 1, p1 - 1), q2 = min(p + 2, p1 - 1), q3 = min(p + 3, p1 - 1);
        int e0s = csr_src[p], e1s = csr_src[q1], e2s = csr_src[q2], e3s = csr_src[q3];
        float2 e0 = *(const float2*)(csr_ea + 2 * (size_t)p);
        float2 e1 = *(const float2*)(csr_ea + 2 * (size_t)q1);
        float2 e2 = *(const float2*)(csr_ea + 2 * (size_t)q2);
        float2 e3 = *(const float2*)(csr_ea + 2 * (size_t)q3);
        float x0 = packed[(size_t)e0s * 64 + xli];
        float x1 = packed[(size_t)e1s * 64 + xli];
        float x2 = packed[(size_t)e2s * 64 + xli];
        float x3 = packed[(size_t)e3s * 64 + xli];
        step(x0, e0, true, den0, acc0);
        step(x1, e1, p + 1 < p1, den1, acc1);
        step(x2, e2, p + 2 < p1, den0, acc0);
        step(x3, e3, p + 3 < p1, den1, acc1);
    }
    {
        float c = fmaxf((float)deg, 1.f);
        float se0 = s0 / c, se1 = s1 / c;
        float xv = packed[(size_t)d * 64 + xli];
        float t = lrelu(xv + xrv + se0 * we0 + se1 * we1, 0.2f) * av;
        float w = __expf(t);
        den0 += w;
        acc0 += w * xv;
    }
    float val = (acc0 + acc1) / (den0 + den1);
#pragma unroll
    for (int w = 1; w < 16; w <<= 1) val += __shfl_xor(val, w);
    if ((threadIdx.x & 15) == 0) {
        float o = val * (1.f / 16.f) + (sel ? sbias[0] : fbias[0]);
        if (sel) mus[d] = o; else fin[d] = o;
    }
}

// ---------------- batchnorm stats ----------------

__global__ void k_bnstats(const float* __restrict__ h, double* __restrict__ stats, int n) {
    int c = threadIdx.x & 63;
    int s0 = blockIdx.x * (blockDim.x >> 6) + (threadIdx.x >> 6);
    int ns = gridDim.x * (blockDim.x >> 6);
    double s = 0.0, s2 = 0.0;
    for (int i = s0; i < n; i += ns) {
        float v = h[(size_t)i * 64 + c];
        s += v;
        s2 += (double)v * v;
    }
    atomicAdd(&stats[c], s);
    atomicAdd(&stats[64 + c], s2);
}

// ---------------- graph-level mean over masked nodes ----------------

__global__ void k_sat_acc(const float* __restrict__ fin, const int* __restrict__ mask,
                          const int* __restrict__ batch,
                          float* __restrict__ sums, float* __restrict__ cnts, int n) {
    int i = blockIdx.x * blockDim.x + threadIdx.x;
    int lane = threadIdx.x & 63;
    int g = (i < n) ? batch[i] : -1;
    float c = (i < n && mask[i] == 0) ? 1.f : 0.f;
    float v = (c > 0.f) ? fin[i] : 0.f;
#pragma unroll
    for (int off = 1; off < 64; off <<= 1) {
        float v2 = __shfl_down(v, off);
        float c2 = __shfl_down(c, off);
        int g2 = __shfl_down(g, off);
        if (lane + off < 64 && g2 == g) { v += v2; c += c2; }
    }
    int gprev = __shfl_up(g, 1);
    bool head = (lane == 0) || (gprev != g);
    if (head && g >= 0 && c > 0.f) {
        atomicAdd(&sums[g], v);
        atomicAdd(&cnts[g], c);
    }
}

__global__ void k_sat_fin(const float* __restrict__ sums, const float* __restrict__ cnts,
                          float* __restrict__ out, int g) {
    int i = threadIdx.x;
    if (i < g) out[i] = sums[i] / fmaxf(cnts[i], 1.f);
}

// ---------------- host ----------------

extern "C" void kernel_launch(void* const* d_in, const int* in_sizes, int n_in,
                              void* d_out, int out_size, void* d_ws, size_t ws_size,
                              hipStream_t stream) {
    const float* x = (const float*)d_in[0];
    const float* eat = (const float*)d_in[1];
    const int* ei = (const int*)d_in[2];
    const int* mask = (const int*)d_in[3];
    const int* batch = (const int*)d_in[4];
    const float* g0_Wl = (const float*)d_in[5];
    const float* g0_bl = (const float*)d_in[6];
    const float* g0_Wr = (const float*)d_in[7];
    const float* g0_br = (const float*)d_in[8];
    const float* g0_We = (const float*)d_in[9];
    const float* g0_att = (const float*)d_in[10];
    const float* g0_bias = (const float*)d_in[11];
    const float* bn_g = (const float*)d_in[12];
    const float* bn_b = (const float*)d_in[13];
    const float* m_Wl = (const float*)d_in[14];
    const float* m_bl = (const float*)d_in[15];
    const float* m_Wr = (const float*)d_in[16];
    const float* m_br = (const float*)d_in[17];
    const float* m_We = (const float*)d_in[18];
    const float* m_att = (const float*)d_in[19];
    const float* m_bias = (const float*)d_in[20];
    const float* f_Wl = (const float*)d_in[21];
    const float* f_bl = (const float*)d_in[22];
    const float* f_Wr = (const float*)d_in[23];
    const float* f_br = (const float*)d_in[24];
    const float* f_We = (const float*)d_in[25];
    const float* f_att = (const float*)d_in[26];
    const float* f_bias = (const float*)d_in[27];
    const float* s_Wl = (const float*)d_in[28];
    const float* s_bl = (const float*)d_in[29];
    const float* s_Wr = (const float*)d_in[30];
    const float* s_br = (const float*)d_in[31];
    const float* s_We = (const float*)d_in[32];
    const float* s_att = (const float*)d_in[33];
    const float* s_bias = (const float*)d_in[34];

    const int N = in_sizes[3];
    const int E = in_sizes[1] / 2;
    const int G = out_size - N;
    const int ITER = in_sizes[14] / 4096;
    const int* srcp = ei;
    const int* dstp = ei + E;

    char* wsb = (char*)d_ws;
    size_t off = 0;
    auto alloc = [&](size_t b) { void* p = wsb + off; off = (off + b + 255) & ~(size_t)255; return p; };
    int* cnt = (int*)alloc((size_t)N * 4);
    int* cursor = (int*)alloc(256);
    double* stats = (double*)alloc(128 * 8);
    float* sums = (float*)alloc((size_t)G * 4);
    float* cnts = (float*)alloc((size_t)G * 4);
    size_t zero_bytes = off;
    int* rank = (int*)alloc((size_t)E * 4);
    int* row_start = (int*)alloc((size_t)N * 4);
    int* csr_src = (int*)alloc((size_t)E * 4);
    float* csr_ea = (float*)alloc((size_t)E * 8);
    float* xlA = (float*)alloc((size_t)N * 256);
    float* xrA = (float*)alloc((size_t)N * 256);
    float* xlB = (float*)alloc((size_t)N * 256);
    float* xrB = (float*)alloc((size_t)N * 256);
    float* hbuf = (float*)alloc((size_t)N * 256);
    float* fin = (float*)alloc((size_t)N * 4);
    (void)ws_size; (void)n_in;

    float* outv = (float*)d_out;  // [0,N) = mus, [N,N+G) = sat

    hipMemsetAsync(d_ws, 0, zero_bytes, stream);
    const int tb = 256;
    const int ggrid = (N * 64 + 255) / 256;
    k_build0<<<(E + N * 64 + tb - 1) / tb, tb, 0, stream>>>(dstp, cnt, rank, E,
                                                            x, g0_Wl, g0_bl, g0_Wr, g0_br,
                                                            xlA, xrA, N);
    k_segoff<<<(N + tb - 1) / tb, tb, 0, stream>>>(cnt, row_start, cursor, N);
    k_scatter<<<(E + tb - 1) / tb, tb, 0, stream>>>(srcp, dstp, eat, rank, row_start,
                                                    csr_src, csr_ea, E);

    k_gat<<<ggrid, tb, 0, stream>>>(xlA, xrA, row_start, cnt, csr_src, csr_ea,
                                    g0_We, g0_att, g0_bias, hbuf, N, 0);
    k_bnstats<<<128, 256, 0, stream>>>(hbuf, stats, N);
    k_proj64<<<(N + 127) / 128, 256, 0, stream>>>(hbuf, m_Wl, m_bl, m_Wr, m_br,
                                                  stats, bn_g, bn_b, xlA, xrA, N);

    float* cur_l = xlA; float* cur_r = xrA;
    float* alt_l = xlB; float* alt_r = xrB;
    for (int l = 0; l < ITER; ++l) {
        if (l < ITER - 1) {
            k_gat_proj<<<ggrid, tb, 0, stream>>>(cur_l, cur_r, row_start, cnt, csr_src, csr_ea,
                                                 m_We + l * 128, m_att + l * 64, m_bias + l * 64,
                                                 m_Wl + (size_t)(l + 1) * 4096, m_bl + (l + 1) * 64,
                                                 m_Wr + (size_t)(l + 1) * 4096, m_br + (l + 1) * 64,
                                                 alt_l, alt_r, N);
        } else {
            k_gat_projfin<<<ggrid, tb, 0, stream>>>(cur_l, cur_r, row_start, cnt, csr_src, csr_ea,
                                                    m_We + l * 128, m_att + l * 64, m_bias + l * 64,
                                                    f_Wl, f_bl, f_Wr, f_br,
                                                    s_Wl, s_bl, s_Wr, s_br,
                                                    alt_l, N);
        }
        float* t;
        t = cur_l; cur_l = alt_l; alt_l = t;
        t = cur_r; cur_r = alt_r; alt_r = t;
    }
    k_gat_final<<<(N * 32 + tb - 1) / tb, tb, 0, stream>>>(cur_l, row_start, cnt, csr_src, csr_ea,
                                                           f_We, s_We, f_att, s_att,
                                                           f_bias, s_bias, fin, outv, N);
    k_sat_acc<<<(N + tb - 1) / tb, tb, 0, stream>>>(fin, mask, batch, sums, cnts, N);
    k_sat_fin<<<1, 64, 0, stream>>>(sums, cnts, outv + N, G);
}